// Round 3
// baseline (408.377 us; speedup 1.0000x reference)
//
#include <hip/hip_runtime.h>
#include <hip/hip_bf16.h>
#include <stdint.h>

#define DDIM 1024
#define NEXP 8
#define SEG  16384   // per-expert token capacity (worst case: every token picks it)

typedef __attribute__((ext_vector_type(8))) short bf16x8;
typedef __attribute__((ext_vector_type(4))) float f32x4;
typedef __attribute__((ext_vector_type(8))) unsigned short u16x8;

#define AS1 __attribute__((address_space(1)))
#define AS3 __attribute__((address_space(3)))

__device__ __forceinline__ unsigned short f2bf(float f) {
    union { float f; unsigned int u; } v; v.f = f;
    unsigned int u = v.u;
    return (unsigned short)((u + 0x7FFFu + ((u >> 16) & 1u)) >> 16);
}
__device__ __forceinline__ float bf2f(unsigned short h) {
    union { unsigned int u; float f; } v; v.u = ((unsigned int)h) << 16;
    return v.f;
}

// ---------------- Kernel A (fused): We fp32->bf16 convert + gating/routing ----
__global__ __launch_bounds__(512) void prep(
    const float* __restrict__ x, const float* __restrict__ Wg,
    const float* __restrict__ bg, const float* __restrict__ We,
    unsigned short* __restrict__ xb, unsigned short* __restrict__ web,
    int* __restrict__ cnt, int* __restrict__ tok_list,
    float* __restrict__ gate_list) {

    __shared__ int   se[64];   // entry = local_token*2 + slot
    __shared__ float sg[64];

    if (blockIdx.x >= 512) {
        size_t idx = ((size_t)(blockIdx.x - 512) * 512 + threadIdx.x) * 8;
        const f32x4* p = (const f32x4*)(We + idx);
        f32x4 a = __builtin_nontemporal_load(p);
        f32x4 b = __builtin_nontemporal_load(p + 1);
        u16x8 h;
        h[0] = f2bf(a[0]); h[1] = f2bf(a[1]); h[2] = f2bf(a[2]); h[3] = f2bf(a[3]);
        h[4] = f2bf(b[0]); h[5] = f2bf(b[1]); h[6] = f2bf(b[2]); h[7] = f2bf(b[3]);
        *(u16x8*)(web + idx) = h;
        return;
    }

    int wave = threadIdx.x >> 6, lane = threadIdx.x & 63;
    int tbase = blockIdx.x * 32;

#pragma unroll
    for (int i = 0; i < 4; i++) {
        int lt = wave * 4 + i;
        int t = tbase + lt;
        const float* xr = x + (size_t)t * DDIM;
        int c0 = lane * 8;

        float4 v0 = ((const float4*)(xr + c0))[0];
        float4 v1 = ((const float4*)(xr + c0))[1];
        float4 v2 = ((const float4*)(xr + c0 + 512))[0];
        float4 v3 = ((const float4*)(xr + c0 + 512))[1];

        u16x8 h0, h1;
        h0[0] = f2bf(v0.x); h0[1] = f2bf(v0.y); h0[2] = f2bf(v0.z); h0[3] = f2bf(v0.w);
        h0[4] = f2bf(v1.x); h0[5] = f2bf(v1.y); h0[6] = f2bf(v1.z); h0[7] = f2bf(v1.w);
        h1[0] = f2bf(v2.x); h1[1] = f2bf(v2.y); h1[2] = f2bf(v2.z); h1[3] = f2bf(v2.w);
        h1[4] = f2bf(v3.x); h1[5] = f2bf(v3.y); h1[6] = f2bf(v3.z); h1[7] = f2bf(v3.w);
        *(u16x8*)(xb + (size_t)t * DDIM + c0) = h0;
        *(u16x8*)(xb + (size_t)t * DDIM + c0 + 512) = h1;

        float acc[NEXP];
#pragma unroll
        for (int e = 0; e < NEXP; e++) {
            const float* wr = Wg + e * DDIM;
            float4 w0 = ((const float4*)(wr + c0))[0];
            float4 w1 = ((const float4*)(wr + c0))[1];
            float4 w2 = ((const float4*)(wr + c0 + 512))[0];
            float4 w3 = ((const float4*)(wr + c0 + 512))[1];
            float s = v0.x*w0.x + v0.y*w0.y + v0.z*w0.z + v0.w*w0.w;
            s += v1.x*w1.x + v1.y*w1.y + v1.z*w1.z + v1.w*w1.w;
            s += v2.x*w2.x + v2.y*w2.y + v2.z*w2.z + v2.w*w2.w;
            s += v3.x*w3.x + v3.y*w3.y + v3.z*w3.z + v3.w*w3.w;
            acc[e] = s;
        }
#pragma unroll
        for (int e = 0; e < NEXP; e++) {
#pragma unroll
            for (int o = 32; o > 0; o >>= 1) acc[e] += __shfl_xor(acc[e], o, 64);
        }

        if (lane == 0) {
            float l1 = -1e30f, l2 = -1e30f; int e1 = 0, e2 = 0;
#pragma unroll
            for (int e = 0; e < NEXP; e++) {
                float le = acc[e] + bg[e];
                if (le > l1) { l2 = l1; e2 = e1; l1 = le; e1 = e; }
                else if (le > l2) { l2 = le; e2 = e; }
            }
            float g1 = 1.0f / (1.0f + __expf(l2 - l1));
            float g2 = 1.0f - g1;
            se[lt * 2]     = e1; sg[lt * 2]     = g1;
            se[lt * 2 + 1] = e2; sg[lt * 2 + 1] = g2;
        }
    }
    __syncthreads();

    if (threadIdx.x < NEXP) {
        int e = threadIdx.x;
        int k = 0;
#pragma unroll 8
        for (int i = 0; i < 64; i++) k += (se[i] == e);
        if (k) {
            int p = atomicAdd(cnt + e, k);
            for (int i = 0; i < 64; i++) {
                if (se[i] == e) {
                    tok_list[e * SEG + p]  = (tbase + (i >> 1)) * 2 + (i & 1);
                    gate_list[e * SEG + p] = sg[i];
                    p++;
                }
            }
        }
    }
}

// ---------------- Kernel C: 8-phase 256x256 gathered GEMM ----------------------
// BM=BN=256, BK=64, 512 thr = 8 waves (2M x 4N), per-wave 128x64 (8x4 frags).
// LDS 128 KB: 2 buffers x (A[256][64] | B[256][64]) bf16, rotation-swizzled
// granules: source granule g of row r lands at slot (g + (r&7)) & 7.
// Phase layout (register surgery vs r2: each phase reads ONLY its own frags;
// peak live frags 32 VGPR, acc in AGPR, no spill under the 256-reg cap):
//   p0: read B0(k0)+A0(k0); stage (kt+1).Ah0 -> other buffer
//   p1: read A1(k0)         ; stage (kt+1).Ah1           [B-regions still live]
//   p2: read B1(k1)+A0(k1)  ; no stage                   [B-regions die here]
//   p3: read A1(k1)         ; stage (kt+2).Bh0+Bh1 -> current buffer
// Each phase: bar; lgkmcnt(0); sched_barrier; setprio(1); 16 MFMA; setprio(0); bar.
// Tile boundary: vmcnt(4) (one B-tile set = 4 loads stays in flight), vmcnt(0)
// only at kt=15. Persistent blocks pull tiles off an atomic queue.

#define STAGE2(P0_, P1_, DSTOFF_, KO_) do {                                    \
    __builtin_amdgcn_global_load_lds((const AS1 void*)((P0_) + (KO_)),         \
        (AS3 void*)(lbuf + (DSTOFF_)), 16, 0, 0);                              \
    __builtin_amdgcn_global_load_lds((const AS1 void*)((P1_) + (KO_)),         \
        (AS3 void*)(lbuf + (DSTOFF_) + 512), 16, 0, 0);                        \
} while (0)

template<bool STORE>
__global__ __launch_bounds__(512, 2) void moe_gemm(
    const unsigned short* __restrict__ xb, const unsigned short* __restrict__ web,
    const float* __restrict__ be, const int* __restrict__ cnt,
    const int* __restrict__ tok_list, const float* __restrict__ gate_list,
    unsigned short* __restrict__ Sb, float* __restrict__ outa,
    int* __restrict__ wctr) {

    extern __shared__ __align__(16) unsigned short lbuf[];  // 131072 B dynamic
    __shared__ int   tok_s[256];
    __shared__ float gate_s[256];
    __shared__ int   s_id;

    int tid = threadIdx.x;
    int w = tid >> 6, lane = tid & 63;
    int wave_m = w >> 2, wave_n = w & 3;
    int mrow = lane & 15, q = lane >> 4;
    int m7 = mrow & 7;
    int s0 = (q + m7) & 7;          // LDS granule slot for k-slice 0
    int s1 = s0 ^ 4;                // k-slice 1
    int aBase = (wave_m * 128 + mrow) * 64;          // elements
    int bBase = 16384 + (wave_n * 64 + mrow) * 64;   // elements
    int gsrc = ((lane & 7) - (lane >> 3)) & 7;       // inverse rotation on source
    int sub8 = lane >> 3;

    for (;;) {
        if (tid == 0) s_id = atomicAdd(wctr, 1);
        __syncthreads();
        int id = s_id;
        int e = 0, c = 0, rem = id;
        while (e < NEXP) {
            c = cnt[e];
            int t_e = ((c + 255) >> 8) << 2;   // m-tiles * 4 n-tiles
            if (rem < t_e) break;
            rem -= t_e; e++;
        }
        if (e == NEXP) return;
        int m0 = (rem >> 2) << 8;
        int n0 = (rem & 3) << 8;

        if (tid < 256) {
            int r = m0 + tid;
            int rc = min(r, c - 1);
            tok_s[tid]  = tok_list[e * SEG + rc];
            gate_s[tid] = (r < c) ? gate_list[e * SEG + rc] : 0.0f;
        }
        __syncthreads();

        // A stage pointers (gathered rows): half h, chunk j covers rows
        // h*128 + w*16 + j*8 + sub8; per-lane source granule pre-rotated.
        const unsigned short* pA[2][2];
#pragma unroll
        for (int h = 0; h < 2; ++h)
#pragma unroll
            for (int j = 0; j < 2; ++j) {
                int row = h * 128 + w * 16 + j * 8 + sub8;
                pA[h][j] = xb + (size_t)(tok_s[row] >> 1) * DDIM + gsrc * 8;
            }
        // B stage base: rows are dense; chunk offsets are compile-time.
        const unsigned short* pB0 = web + ((size_t)e << 20) +
            (size_t)(n0 + w * 16 + sub8) * DDIM + gsrc * 8;

        f32x4 acc[8][4];
#pragma unroll
        for (int mi = 0; mi < 8; ++mi)
#pragma unroll
            for (int ni = 0; ni < 4; ++ni) acc[mi][ni] = (f32x4){0.f, 0.f, 0.f, 0.f};

        // ---- prologue (order matters for vmcnt): K0.B[4], K0.A[4], K1.B[4] ----
        STAGE2(pB0,               pB0 + 8 * DDIM,               16384 + w * 1024, 0);
        STAGE2(pB0 + 128 * DDIM,  pB0 + 136 * DDIM,             16384 + 8192 + w * 1024, 0);
        STAGE2(pA[0][0], pA[0][1], 0 + w * 1024, 0);
        STAGE2(pA[1][0], pA[1][1], 8192 + w * 1024, 0);
        STAGE2(pB0,               pB0 + 8 * DDIM,               32768 + 16384 + w * 1024, 64);
        STAGE2(pB0 + 128 * DDIM,  pB0 + 136 * DDIM,             32768 + 16384 + 8192 + w * 1024, 64);

#pragma unroll 2
        for (int kt = 0; kt < 16; ++kt) {
            if (kt == 15) { asm volatile("s_waitcnt vmcnt(0)" ::: "memory"); }
            else          { asm volatile("s_waitcnt vmcnt(4)" ::: "memory"); }
            __builtin_amdgcn_s_barrier();

            int bufo = (kt & 1) << 15;
            int nb   = ((kt + 1) & 1) << 15;
            int ko1  = (kt + 1) << 6;
            int ko2  = (kt + 2) << 6;

            bf16x8 A0[4], A1[4], B0[4], B1[4];

            // ---- p0: read B0(k0)+A0(k0); stage (kt+1).Ah0 ----
#pragma unroll
            for (int ni = 0; ni < 4; ++ni)
                B0[ni] = *(const bf16x8*)(lbuf + bufo + bBase + ni * 1024 + s0 * 8);
#pragma unroll
            for (int mi = 0; mi < 4; ++mi)
                A0[mi] = *(const bf16x8*)(lbuf + bufo + aBase + mi * 1024 + s0 * 8);
            if (kt < 15) STAGE2(pA[0][0], pA[0][1], nb + w * 1024, ko1);
            __builtin_amdgcn_s_barrier();
            asm volatile("s_waitcnt lgkmcnt(0)" ::: "memory");
            __builtin_amdgcn_sched_barrier(0);
            __builtin_amdgcn_s_setprio(1);
#pragma unroll
            for (int mi = 0; mi < 4; ++mi)
#pragma unroll
                for (int ni = 0; ni < 4; ++ni)
                    acc[mi][ni] = __builtin_amdgcn_mfma_f32_16x16x32_bf16(
                        A0[mi], B0[ni], acc[mi][ni], 0, 0, 0);
            __builtin_amdgcn_s_setprio(0);
            __builtin_amdgcn_s_barrier();

            // ---- p1: read A1(k0); stage (kt+1).Ah1 ----
#pragma unroll
            for (int mi = 0; mi < 4; ++mi)
                A1[mi] = *(const bf16x8*)(lbuf + bufo + aBase + (mi + 4) * 1024 + s0 * 8);
            if (kt < 15) STAGE2(pA[1][0], pA[1][1], nb + 8192 + w * 1024, ko1);
            __builtin_amdgcn_s_barrier();
            asm volatile("s_waitcnt lgkmcnt(0)" ::: "memory");
            __builtin_amdgcn_sched_barrier(0);
            __builtin_amdgcn_s_setprio(1);
#pragma unroll
            for (int mi = 0; mi < 4; ++mi)
#pragma unroll
                for (int ni = 0; ni < 4; ++ni)
                    acc[mi + 4][ni] = __builtin_amdgcn_mfma_f32_16x16x32_bf16(
                        A1[mi], B0[ni], acc[mi + 4][ni], 0, 0, 0);
            __builtin_amdgcn_s_setprio(0);
            __builtin_amdgcn_s_barrier();

            // ---- p2: read B1(k1)+A0(k1); no stage ----
#pragma unroll
            for (int ni = 0; ni < 4; ++ni)
                B1[ni] = *(const bf16x8*)(lbuf + bufo + bBase + ni * 1024 + s1 * 8);
#pragma unroll
            for (int mi = 0; mi < 4; ++mi)
                A0[mi] = *(const bf16x8*)(lbuf + bufo + aBase + mi * 1024 + s1 * 8);
            __builtin_amdgcn_s_barrier();
            asm volatile("s_waitcnt lgkmcnt(0)" ::: "memory");
            __builtin_amdgcn_sched_barrier(0);
            __builtin_amdgcn_s_setprio(1);
#pragma unroll
            for (int mi = 0; mi < 4; ++mi)
#pragma unroll
                for (int ni = 0; ni < 4; ++ni)
                    acc[mi][ni] = __builtin_amdgcn_mfma_f32_16x16x32_bf16(
                        A0[mi], B1[ni], acc[mi][ni], 0, 0, 0);
            __builtin_amdgcn_s_setprio(0);
            __builtin_amdgcn_s_barrier();

            // ---- p3: read A1(k1); stage (kt+2).Bh0+Bh1 (B-regions died at p2) ----
#pragma unroll
            for (int mi = 0; mi < 4; ++mi)
                A1[mi] = *(const bf16x8*)(lbuf + bufo + aBase + (mi + 4) * 1024 + s1 * 8);
            if (kt < 14) {
                STAGE2(pB0,              pB0 + 8 * DDIM,   bufo + 16384 + w * 1024, ko2);
                STAGE2(pB0 + 128 * DDIM, pB0 + 136 * DDIM, bufo + 16384 + 8192 + w * 1024, ko2);
            }
            __builtin_amdgcn_s_barrier();
            asm volatile("s_waitcnt lgkmcnt(0)" ::: "memory");
            __builtin_amdgcn_sched_barrier(0);
            __builtin_amdgcn_s_setprio(1);
#pragma unroll
            for (int mi = 0; mi < 4; ++mi)
#pragma unroll
                for (int ni = 0; ni < 4; ++ni)
                    acc[mi + 4][ni] = __builtin_amdgcn_mfma_f32_16x16x32_bf16(
                        A1[mi], B1[ni], acc[mi + 4][ni], 0, 0, 0);
            __builtin_amdgcn_s_setprio(0);
            // no trailing barrier: next K-tile boundary (vmcnt+barrier) provides
        }

        if (STORE) {
            // ---- stage C-tile (gate*(acc+bias), bf16) into LDS, XOR-swizzled ----
            __syncthreads();
#pragma unroll
            for (int ni = 0; ni < 4; ++ni) {
                int col = wave_n * 64 + ni * 16 + mrow;
                float bias = be[e * DDIM + n0 + col];
                int cg = col >> 3, cl = col & 7;
#pragma unroll
                for (int mi = 0; mi < 8; ++mi) {
#pragma unroll
                    for (int r = 0; r < 4; ++r) {
                        int row = wave_m * 128 + mi * 16 + q * 4 + r;
                        lbuf[row * 256 + ((cg ^ (row & 7)) << 3) + cl] =
                            f2bf(gate_s[row] * (acc[mi][ni][r] + bias));
                    }
                }
            }
            __syncthreads();
            // ---- coalesced 16B stores: 256x32 granules / 512 threads = 16 iters ----
#pragma unroll
            for (int j = 0; j < 16; ++j) {
                int t = j * 512 + tid;
                int row = t >> 5, gc = t & 31;
                u16x8 vv = *(const u16x8*)&lbuf[row * 256 + ((gc ^ (row & 7)) << 3)];
                if (m0 + row < c)
                    *(u16x8*)(Sb + (size_t)tok_s[row] * DDIM + n0 + gc * 8) = vv;
            }
        } else {
            __syncthreads();
#pragma unroll
            for (int ni = 0; ni < 4; ++ni) {
                int col = n0 + wave_n * 64 + ni * 16 + mrow;
                float bias = be[e * DDIM + col];
#pragma unroll
                for (int mi = 0; mi < 8; ++mi) {
#pragma unroll
                    for (int r = 0; r < 4; ++r) {
                        int rl = wave_m * 128 + mi * 16 + q * 4 + r;
                        if (m0 + rl < c)
                            atomicAdd(outa + (size_t)(tok_s[rl] >> 1) * DDIM + col,
                                      gate_s[rl] * (acc[mi][ni][r] + bias));
                    }
                }
            }
        }
    }
}

// ---------------- Kernel D: combine the two slot rows per token ----------------
__global__ void combine(const unsigned short* __restrict__ S, float* __restrict__ out) {
    size_t i = (size_t)blockIdx.x * 256 + threadIdx.x;
    size_t t = i >> 7;
    size_t g = i & 127;
    const u16x8* r0 = (const u16x8*)(S + t * 2 * DDIM) + g;
    const u16x8* r1 = (const u16x8*)(S + (t * 2 + 1) * DDIM) + g;
    u16x8 a = *r0;
    u16x8 b = *r1;
    f32x4 o0, o1;
#pragma unroll
    for (int k = 0; k < 4; k++) o0[k] = bf2f(a[k]) + bf2f(b[k]);
#pragma unroll
    for (int k = 0; k < 4; k++) o1[k] = bf2f(a[4 + k]) + bf2f(b[4 + k]);
    f32x4* op = (f32x4*)(out + t * DDIM + g * 8);
    __builtin_nontemporal_store(o0, op);
    __builtin_nontemporal_store(o1, op + 1);
}

extern "C" void kernel_launch(void* const* d_in, const int* in_sizes, int n_in,
                              void* d_out, int out_size, void* d_ws, size_t ws_size,
                              hipStream_t stream) {
    const float* x  = (const float*)d_in[0];
    const float* Wg = (const float*)d_in[1];
    const float* bg = (const float*)d_in[2];
    const float* We = (const float*)d_in[3];
    const float* be = (const float*)d_in[4];
    float* out = (float*)d_out;

    char* ws = (char*)d_ws;
    unsigned short* xb  = (unsigned short*)ws;                          // 32 MB
    unsigned short* web = (unsigned short*)(ws + 33554432);             // 16 MB
    int*   tok_list  = (int*)(ws + 33554432 + 16777216);                // 512 KB
    float* gate_list = (float*)(ws + 33554432 + 16777216 + 524288);     // 512 KB
    int*   cnt       = (int*)(ws + 33554432 + 16777216 + 1048576);      // cnt[8] + wctr
    unsigned short* S = (unsigned short*)(ws + 52428800);               // 67.1 MB

    int* wctr = cnt + NEXP;

    const size_t NEED = 52428800ull + (size_t)32768 * DDIM * 2;         // ~119.5 MB

    // one-time opt-in for 128KB dynamic LDS
    static bool attr_done = false;
    if (!attr_done) {
        hipFuncSetAttribute(reinterpret_cast<const void*>(moe_gemm<true>),
                            hipFuncAttributeMaxDynamicSharedMemorySize, 131072);
        hipFuncSetAttribute(reinterpret_cast<const void*>(moe_gemm<false>),
                            hipFuncAttributeMaxDynamicSharedMemorySize, 131072);
        attr_done = true;
    }

    hipMemsetAsync(cnt, 0, (NEXP + 1) * sizeof(int), stream);

    // 512 gating blocks + 2048 convert blocks in one dispatch
    prep<<<2560, 512, 0, stream>>>(x, Wg, bg, We, xb, web, cnt, tok_list, gate_list);

    if (ws_size >= NEED) {
        // persistent: 1 block/CU, tiles pulled from atomic queue
        moe_gemm<true><<<256, 512, 131072, stream>>>(
            xb, web, be, cnt, tok_list, gate_list, S, nullptr, wctr);
        combine<<<8192, 256, 0, stream>>>(S, out);
    } else {
        hipMemsetAsync(d_out, 0, (size_t)out_size * sizeof(float), stream);
        moe_gemm<false><<<256, 512, 131072, stream>>>(
            xb, web, be, cnt, tok_list, gate_list, nullptr, out, wctr);
    }
}

// Round 4
// 375.304 us; speedup vs baseline: 1.0881x; 1.0881x over previous
//
#include <hip/hip_runtime.h>
#include <hip/hip_bf16.h>
#include <stdint.h>

#define DDIM 1024
#define NEXP 8
#define SEG  16384   // per-expert token capacity (worst case: every token picks it)

typedef __attribute__((ext_vector_type(8))) short bf16x8;
typedef __attribute__((ext_vector_type(4))) float f32x4;
typedef __attribute__((ext_vector_type(8))) unsigned short u16x8;

#define AS1 __attribute__((address_space(1)))
#define AS3 __attribute__((address_space(3)))

__device__ __forceinline__ unsigned short f2bf(float f) {
    union { float f; unsigned int u; } v; v.f = f;
    unsigned int u = v.u;
    return (unsigned short)((u + 0x7FFFu + ((u >> 16) & 1u)) >> 16);
}
__device__ __forceinline__ float bf2f(unsigned short h) {
    union { unsigned int u; float f; } v; v.u = ((unsigned int)h) << 16;
    return v.f;
}

// ---------------- Kernel A (fused): We fp32->bf16 convert + gating/routing ----
__global__ __launch_bounds__(512) void prep(
    const float* __restrict__ x, const float* __restrict__ Wg,
    const float* __restrict__ bg, const float* __restrict__ We,
    unsigned short* __restrict__ xb, unsigned short* __restrict__ web,
    int* __restrict__ cnt, int* __restrict__ tok_list,
    float* __restrict__ gate_list) {

    __shared__ int   se[64];   // entry = local_token*2 + slot
    __shared__ float sg[64];

    if (blockIdx.x >= 512) {
        size_t idx = ((size_t)(blockIdx.x - 512) * 512 + threadIdx.x) * 8;
        const f32x4* p = (const f32x4*)(We + idx);
        f32x4 a = __builtin_nontemporal_load(p);
        f32x4 b = __builtin_nontemporal_load(p + 1);
        u16x8 h;
        h[0] = f2bf(a[0]); h[1] = f2bf(a[1]); h[2] = f2bf(a[2]); h[3] = f2bf(a[3]);
        h[4] = f2bf(b[0]); h[5] = f2bf(b[1]); h[6] = f2bf(b[2]); h[7] = f2bf(b[3]);
        *(u16x8*)(web + idx) = h;
        return;
    }

    int wave = threadIdx.x >> 6, lane = threadIdx.x & 63;
    int tbase = blockIdx.x * 32;

#pragma unroll
    for (int i = 0; i < 4; i++) {
        int lt = wave * 4 + i;
        int t = tbase + lt;
        const float* xr = x + (size_t)t * DDIM;
        int c0 = lane * 8;

        float4 v0 = ((const float4*)(xr + c0))[0];
        float4 v1 = ((const float4*)(xr + c0))[1];
        float4 v2 = ((const float4*)(xr + c0 + 512))[0];
        float4 v3 = ((const float4*)(xr + c0 + 512))[1];

        u16x8 h0, h1;
        h0[0] = f2bf(v0.x); h0[1] = f2bf(v0.y); h0[2] = f2bf(v0.z); h0[3] = f2bf(v0.w);
        h0[4] = f2bf(v1.x); h0[5] = f2bf(v1.y); h0[6] = f2bf(v1.z); h0[7] = f2bf(v1.w);
        h1[0] = f2bf(v2.x); h1[1] = f2bf(v2.y); h1[2] = f2bf(v2.z); h1[3] = f2bf(v2.w);
        h1[4] = f2bf(v3.x); h1[5] = f2bf(v3.y); h1[6] = f2bf(v3.z); h1[7] = f2bf(v3.w);
        *(u16x8*)(xb + (size_t)t * DDIM + c0) = h0;
        *(u16x8*)(xb + (size_t)t * DDIM + c0 + 512) = h1;

        float acc[NEXP];
#pragma unroll
        for (int e = 0; e < NEXP; e++) {
            const float* wr = Wg + e * DDIM;
            float4 w0 = ((const float4*)(wr + c0))[0];
            float4 w1 = ((const float4*)(wr + c0))[1];
            float4 w2 = ((const float4*)(wr + c0 + 512))[0];
            float4 w3 = ((const float4*)(wr + c0 + 512))[1];
            float s = v0.x*w0.x + v0.y*w0.y + v0.z*w0.z + v0.w*w0.w;
            s += v1.x*w1.x + v1.y*w1.y + v1.z*w1.z + v1.w*w1.w;
            s += v2.x*w2.x + v2.y*w2.y + v2.z*w2.z + v2.w*w2.w;
            s += v3.x*w3.x + v3.y*w3.y + v3.z*w3.z + v3.w*w3.w;
            acc[e] = s;
        }
#pragma unroll
        for (int e = 0; e < NEXP; e++) {
#pragma unroll
            for (int o = 32; o > 0; o >>= 1) acc[e] += __shfl_xor(acc[e], o, 64);
        }

        if (lane == 0) {
            float l1 = -1e30f, l2 = -1e30f; int e1 = 0, e2 = 0;
#pragma unroll
            for (int e = 0; e < NEXP; e++) {
                float le = acc[e] + bg[e];
                if (le > l1) { l2 = l1; e2 = e1; l1 = le; e1 = e; }
                else if (le > l2) { l2 = le; e2 = e; }
            }
            float g1 = 1.0f / (1.0f + __expf(l2 - l1));
            float g2 = 1.0f - g1;
            se[lt * 2]     = e1; sg[lt * 2]     = g1;
            se[lt * 2 + 1] = e2; sg[lt * 2 + 1] = g2;
        }
    }
    __syncthreads();

    if (threadIdx.x < NEXP) {
        int e = threadIdx.x;
        int k = 0;
#pragma unroll 8
        for (int i = 0; i < 64; i++) k += (se[i] == e);
        if (k) {
            int p = atomicAdd(cnt + e, k);
            for (int i = 0; i < 64; i++) {
                if (se[i] == e) {
                    tok_list[e * SEG + p]  = (tbase + (i >> 1)) * 2 + (i & 1);
                    gate_list[e * SEG + p] = sg[i];
                    p++;
                }
            }
        }
    }
}

// ---------------- Kernel C: per-expert gathered GEMM, bf16 MFMA ----------------
// Round-1 proven structure: BM=128, BN=256, BK=32, 256 thr = 4 waves, each wave
// owns 128x64 (8x4 frags). LDS ring of 3 slots (A[128][32]+B[256][32] = 24KB),
// prefetch depth 2 K-tiles, ONE s_barrier per K-tile, counted vmcnt(6).
// Rotation swizzle slot=(g+(row>>1))&3 with inverse rotation pre-applied to the
// per-lane GLOBAL source address (linear wave-uniform LDS dst for gload_lds).
// NEW vs r1: persistent blocks (grid=512 -> 2 blocks/CU for TLP: two blocks
// interleave barrier/vmcnt waits with each other's MFMA) pulling tiles off an
// atomic queue, n-fastest order so an A-panel's 4 n-tiles run near-concurrently.

__device__ __forceinline__ void stage_tile(const unsigned short* const* sp,
                                           unsigned short* lbase, int wave, int kt) {
    int ko = kt << 5;   // kt * 32 elements
#pragma unroll
    for (int j = 0; j < 6; ++j) {
        __builtin_amdgcn_global_load_lds(
            (const AS1 void*)(sp[j] + ko),
            (AS3 void*)(lbase + (wave * 6 + j) * 512),
            16, 0, 0);
    }
}

__device__ __forceinline__ void tile_mma(const unsigned short* ba, int aoff, int boff,
                                         f32x4 (&acc)[8][4]) {
    bf16x8 af[8], bf[4];
#pragma unroll
    for (int mi = 0; mi < 8; ++mi) af[mi] = *(const bf16x8*)(ba + aoff + mi * 512);
#pragma unroll
    for (int ni = 0; ni < 4; ++ni) bf[ni] = *(const bf16x8*)(ba + boff + ni * 512);
    __builtin_amdgcn_s_setprio(1);
#pragma unroll
    for (int mi = 0; mi < 8; ++mi)
#pragma unroll
        for (int ni = 0; ni < 4; ++ni)
            acc[mi][ni] = __builtin_amdgcn_mfma_f32_16x16x32_bf16(
                af[mi], bf[ni], acc[mi][ni], 0, 0, 0);
    __builtin_amdgcn_s_setprio(0);
}

template<bool STORE>
__global__ __launch_bounds__(256, 2) void moe_gemm(
    const unsigned short* __restrict__ xb, const unsigned short* __restrict__ web,
    const float* __restrict__ be, const int* __restrict__ cnt,
    const int* __restrict__ tok_list, const float* __restrict__ gate_list,
    unsigned short* __restrict__ Sb, float* __restrict__ outa,
    int* __restrict__ wctr) {

    extern __shared__ __align__(16) unsigned short lbuf[];  // 3 slots x 12288 el = 72 KB
    __shared__ int   tok_s[128];
    __shared__ float gate_s[128];
    __shared__ int   s_id;

    int tid = threadIdx.x;
    int wave = tid >> 6, lane = tid & 63;

    // LDS read offsets (elements); rotation slot for 16-aligned rows = (mrow>>1)&3
    int mrow = lane & 15, q = lane >> 4;
    int ksl  = ((q + (mrow >> 1)) & 3) << 3;
    int aoff = mrow * 32 + ksl;                      // + mi*512
    int boff = 4096 + wave * 2048 + mrow * 32 + ksl; // + ni*512
    // staging: lane covers row sub=lane>>2, dst slot lane&3; inverse-rotated src granule
    int g0  = ((lane & 3) - ((lane >> 3) & 3)) & 3;
    int sub = lane >> 2;

    for (;;) {
        if (tid == 0) s_id = atomicAdd(wctr, 1);
        __syncthreads();                    // also protects tok_s/lbuf reuse
        int id = s_id;
        int e = 0, c = 0, rem = id;
        while (e < NEXP) {
            c = cnt[e];
            int t_e = ((c + 127) >> 7) << 2;   // m-tiles * 4 n-tiles
            if (rem < t_e) break;
            rem -= t_e; e++;
        }
        if (e == NEXP) return;
        int m0 = (rem >> 2) << 7;   // n fastest: A-panel's 4 n-tiles adjacent ids
        int n0 = (rem & 3) << 8;

        if (tid < 128) {
            int r = m0 + tid;
            int rc = min(r, c - 1);
            tok_s[tid]  = tok_list[e * SEG + rc];
            gate_s[tid] = (r < c) ? gate_list[e * SEG + rc] : 0.0f;
        }
        __syncthreads();

        // staging source pointers: chunk ch = wave*6+j; ch<8 -> A rows ch*16+sub,
        // ch>=8 -> B rows (ch-8)*16+sub; per-lane source granule pre-rotated.
        const unsigned short* sp[6];
#pragma unroll
        for (int j = 0; j < 6; ++j) {
            int ch = wave * 6 + j;
            int arow = min((ch << 4) + sub, 127);
            int brow = ((ch - 8) << 4) + sub;
            const unsigned short* pa = xb + (size_t)(tok_s[arow] >> 1) * DDIM + g0 * 8;
            const unsigned short* pb = web + ((size_t)e << 20) +
                                       (size_t)(n0 + brow) * DDIM + g0 * 8;
            sp[j] = (ch < 8) ? pa : pb;
        }

        f32x4 acc[8][4];
#pragma unroll
        for (int mi = 0; mi < 8; ++mi)
#pragma unroll
            for (int ni = 0; ni < 4; ++ni) acc[mi][ni] = (f32x4){0.f, 0.f, 0.f, 0.f};

        // ---- prologue: stage K-tiles 0,1 (6 loads each; 12 outstanding) ----
        stage_tile(sp, lbuf,         wave, 0);
        stage_tile(sp, lbuf + 12288, wave, 1);

        // ---- main loop: K-tiles 0..29, stage kt+2, wait vmcnt(6) ----
        for (int kb = 0; kb < 10; ++kb) {
#pragma unroll
            for (int u = 0; u < 3; ++u) {
                int kt = kb * 3 + u;
                asm volatile("s_waitcnt vmcnt(6)" ::: "memory");
                __builtin_amdgcn_s_barrier();
                asm volatile("" ::: "memory");
                stage_tile(sp, lbuf + ((u + 2) % 3) * 12288, wave, kt + 2);
                tile_mma(lbuf + u * 12288, aoff, boff, acc);
            }
        }
        // ---- epilogue tiles 30 (slot 0) and 31 (slot 1) ----
        asm volatile("s_waitcnt vmcnt(6)" ::: "memory");
        __builtin_amdgcn_s_barrier();
        asm volatile("" ::: "memory");
        tile_mma(lbuf, aoff, boff, acc);

        asm volatile("s_waitcnt vmcnt(0)" ::: "memory");
        __builtin_amdgcn_s_barrier();
        asm volatile("" ::: "memory");
        tile_mma(lbuf + 12288, aoff, boff, acc);

        if (STORE) {
            // ---- stage C-tile (gate*(acc+bias), bf16) into LDS, XOR-swizzled ----
            __syncthreads();
#pragma unroll
            for (int ni = 0; ni < 4; ++ni) {
                int col = wave * 64 + ni * 16 + mrow;        // tile-local col (0..255)
                float bias = be[e * DDIM + n0 + col];
                int cg = col >> 3, cl = col & 7;
#pragma unroll
                for (int mi = 0; mi < 8; ++mi) {
#pragma unroll
                    for (int r = 0; r < 4; ++r) {
                        int row = mi * 16 + q * 4 + r;       // tile-local row (0..127)
                        lbuf[row * 256 + ((cg ^ (row & 7)) << 3) + cl] =
                            f2bf(gate_s[row] * (acc[mi][ni][r] + bias));
                    }
                }
            }
            __syncthreads();
            // ---- coalesced 16B stores: 128x32 granules / 256 threads = 16 iters ----
#pragma unroll
            for (int j = 0; j < 16; ++j) {
                int t = j * 256 + tid;
                int row = t >> 5, gc = t & 31;
                u16x8 vv = *(const u16x8*)&lbuf[row * 256 + ((gc ^ (row & 7)) << 3)];
                if (m0 + row < c)
                    *(u16x8*)(Sb + (size_t)tok_s[row] * DDIM + n0 + gc * 8) = vv;
            }
        } else {
            __syncthreads();
#pragma unroll
            for (int ni = 0; ni < 4; ++ni) {
                int col = n0 + wave * 64 + ni * 16 + mrow;
                float bias = be[e * DDIM + col];
#pragma unroll
                for (int mi = 0; mi < 8; ++mi) {
#pragma unroll
                    for (int r = 0; r < 4; ++r) {
                        int rl = mi * 16 + q * 4 + r;
                        if (m0 + rl < c)
                            atomicAdd(outa + (size_t)(tok_s[rl] >> 1) * DDIM + col,
                                      gate_s[rl] * (acc[mi][ni][r] + bias));
                    }
                }
            }
        }
    }
}

// ---------------- Kernel D: combine the two slot rows per token ----------------
__global__ void combine(const unsigned short* __restrict__ S, float* __restrict__ out) {
    size_t i = (size_t)blockIdx.x * 256 + threadIdx.x;
    size_t t = i >> 7;
    size_t g = i & 127;
    const u16x8* r0 = (const u16x8*)(S + t * 2 * DDIM) + g;
    const u16x8* r1 = (const u16x8*)(S + (t * 2 + 1) * DDIM) + g;
    u16x8 a = *r0;
    u16x8 b = *r1;
    f32x4 o0, o1;
#pragma unroll
    for (int k = 0; k < 4; k++) o0[k] = bf2f(a[k]) + bf2f(b[k]);
#pragma unroll
    for (int k = 0; k < 4; k++) o1[k] = bf2f(a[4 + k]) + bf2f(b[4 + k]);
    f32x4* op = (f32x4*)(out + t * DDIM + g * 8);
    __builtin_nontemporal_store(o0, op);
    __builtin_nontemporal_store(o1, op + 1);
}

extern "C" void kernel_launch(void* const* d_in, const int* in_sizes, int n_in,
                              void* d_out, int out_size, void* d_ws, size_t ws_size,
                              hipStream_t stream) {
    const float* x  = (const float*)d_in[0];
    const float* Wg = (const float*)d_in[1];
    const float* bg = (const float*)d_in[2];
    const float* We = (const float*)d_in[3];
    const float* be = (const float*)d_in[4];
    float* out = (float*)d_out;

    char* ws = (char*)d_ws;
    unsigned short* xb  = (unsigned short*)ws;                          // 32 MB
    unsigned short* web = (unsigned short*)(ws + 33554432);             // 16 MB
    int*   tok_list  = (int*)(ws + 33554432 + 16777216);                // 512 KB
    float* gate_list = (float*)(ws + 33554432 + 16777216 + 524288);     // 512 KB
    int*   cnt       = (int*)(ws + 33554432 + 16777216 + 1048576);      // cnt[8] + wctr
    unsigned short* S = (unsigned short*)(ws + 52428800);               // 67.1 MB

    int* wctr = cnt + NEXP;

    const size_t NEED = 52428800ull + (size_t)32768 * DDIM * 2;         // ~119.5 MB

    // one-time opt-in for 72KB dynamic LDS
    static bool attr_done = false;
    if (!attr_done) {
        hipFuncSetAttribute(reinterpret_cast<const void*>(moe_gemm<true>),
                            hipFuncAttributeMaxDynamicSharedMemorySize, 73728);
        hipFuncSetAttribute(reinterpret_cast<const void*>(moe_gemm<false>),
                            hipFuncAttributeMaxDynamicSharedMemorySize, 73728);
        attr_done = true;
    }

    hipMemsetAsync(cnt, 0, (NEXP + 1) * sizeof(int), stream);

    // 512 gating blocks + 2048 convert blocks in one dispatch
    prep<<<2560, 512, 0, stream>>>(x, Wg, bg, We, xb, web, cnt, tok_list, gate_list);

    if (ws_size >= NEED) {
        // persistent: 2 blocks/CU, tiles pulled from atomic queue
        moe_gemm<true><<<512, 256, 73728, stream>>>(
            xb, web, be, cnt, tok_list, gate_list, S, nullptr, wctr);
        combine<<<8192, 256, 0, stream>>>(S, out);
    } else {
        hipMemsetAsync(d_out, 0, (size_t)out_size * sizeof(float), stream);
        moe_gemm<false><<<512, 256, 73728, stream>>>(
            xb, web, be, cnt, tok_list, gate_list, nullptr, out, wctr);
    }
}

// Round 5
// 272.484 us; speedup vs baseline: 1.4987x; 1.3773x over previous
//
#include <hip/hip_runtime.h>
#include <hip/hip_bf16.h>
#include <stdint.h>

#define DDIM 1024
#define NEXP 8
#define SEG  16384   // per-expert token capacity (worst case: every token picks it)

typedef __attribute__((ext_vector_type(8))) short bf16x8;
typedef __attribute__((ext_vector_type(4))) float f32x4;
typedef __attribute__((ext_vector_type(8))) unsigned short u16x8;

#define AS1 __attribute__((address_space(1)))
#define AS3 __attribute__((address_space(3)))

__device__ __forceinline__ unsigned short f2bf(float f) {
    union { float f; unsigned int u; } v; v.f = f;
    unsigned int u = v.u;
    return (unsigned short)((u + 0x7FFFu + ((u >> 16) & 1u)) >> 16);
}
__device__ __forceinline__ float bf2f(unsigned short h) {
    union { unsigned int u; float f; } v; v.u = ((unsigned int)h) << 16;
    return v.f;
}

// ---------------- Kernel A (fused): We fp32->bf16 convert + gating/routing ----
__global__ __launch_bounds__(512) void prep(
    const float* __restrict__ x, const float* __restrict__ Wg,
    const float* __restrict__ bg, const float* __restrict__ We,
    unsigned short* __restrict__ xb, unsigned short* __restrict__ web,
    int* __restrict__ cnt, int* __restrict__ tok_list,
    float* __restrict__ gate_list) {

    __shared__ int   se[64];   // entry = local_token*2 + slot
    __shared__ float sg[64];

    if (blockIdx.x >= 512) {
        size_t idx = ((size_t)(blockIdx.x - 512) * 512 + threadIdx.x) * 8;
        const f32x4* p = (const f32x4*)(We + idx);
        f32x4 a = __builtin_nontemporal_load(p);
        f32x4 b = __builtin_nontemporal_load(p + 1);
        u16x8 h;
        h[0] = f2bf(a[0]); h[1] = f2bf(a[1]); h[2] = f2bf(a[2]); h[3] = f2bf(a[3]);
        h[4] = f2bf(b[0]); h[5] = f2bf(b[1]); h[6] = f2bf(b[2]); h[7] = f2bf(b[3]);
        *(u16x8*)(web + idx) = h;
        return;
    }

    int wave = threadIdx.x >> 6, lane = threadIdx.x & 63;
    int tbase = blockIdx.x * 32;

#pragma unroll
    for (int i = 0; i < 4; i++) {
        int lt = wave * 4 + i;
        int t = tbase + lt;
        const float* xr = x + (size_t)t * DDIM;
        int c0 = lane * 8;

        float4 v0 = ((const float4*)(xr + c0))[0];
        float4 v1 = ((const float4*)(xr + c0))[1];
        float4 v2 = ((const float4*)(xr + c0 + 512))[0];
        float4 v3 = ((const float4*)(xr + c0 + 512))[1];

        u16x8 h0, h1;
        h0[0] = f2bf(v0.x); h0[1] = f2bf(v0.y); h0[2] = f2bf(v0.z); h0[3] = f2bf(v0.w);
        h0[4] = f2bf(v1.x); h0[5] = f2bf(v1.y); h0[6] = f2bf(v1.z); h0[7] = f2bf(v1.w);
        h1[0] = f2bf(v2.x); h1[1] = f2bf(v2.y); h1[2] = f2bf(v2.z); h1[3] = f2bf(v2.w);
        h1[4] = f2bf(v3.x); h1[5] = f2bf(v3.y); h1[6] = f2bf(v3.z); h1[7] = f2bf(v3.w);
        *(u16x8*)(xb + (size_t)t * DDIM + c0) = h0;
        *(u16x8*)(xb + (size_t)t * DDIM + c0 + 512) = h1;

        float acc[NEXP];
#pragma unroll
        for (int e = 0; e < NEXP; e++) {
            const float* wr = Wg + e * DDIM;
            float4 w0 = ((const float4*)(wr + c0))[0];
            float4 w1 = ((const float4*)(wr + c0))[1];
            float4 w2 = ((const float4*)(wr + c0 + 512))[0];
            float4 w3 = ((const float4*)(wr + c0 + 512))[1];
            float s = v0.x*w0.x + v0.y*w0.y + v0.z*w0.z + v0.w*w0.w;
            s += v1.x*w1.x + v1.y*w1.y + v1.z*w1.z + v1.w*w1.w;
            s += v2.x*w2.x + v2.y*w2.y + v2.z*w2.z + v2.w*w2.w;
            s += v3.x*w3.x + v3.y*w3.y + v3.z*w3.z + v3.w*w3.w;
            acc[e] = s;
        }
#pragma unroll
        for (int e = 0; e < NEXP; e++) {
#pragma unroll
            for (int o = 32; o > 0; o >>= 1) acc[e] += __shfl_xor(acc[e], o, 64);
        }

        if (lane == 0) {
            float l1 = -1e30f, l2 = -1e30f; int e1 = 0, e2 = 0;
#pragma unroll
            for (int e = 0; e < NEXP; e++) {
                float le = acc[e] + bg[e];
                if (le > l1) { l2 = l1; e2 = e1; l1 = le; e1 = e; }
                else if (le > l2) { l2 = le; e2 = e; }
            }
            float g1 = 1.0f / (1.0f + __expf(l2 - l1));
            float g2 = 1.0f - g1;
            se[lt * 2]     = e1; sg[lt * 2]     = g1;
            se[lt * 2 + 1] = e2; sg[lt * 2 + 1] = g2;
        }
    }
    __syncthreads();

    if (threadIdx.x < NEXP) {
        int e = threadIdx.x;
        int k = 0;
#pragma unroll 8
        for (int i = 0; i < 64; i++) k += (se[i] == e);
        if (k) {
            int p = atomicAdd(cnt + e, k);
            for (int i = 0; i < 64; i++) {
                if (se[i] == e) {
                    tok_list[e * SEG + p]  = (tbase + (i >> 1)) * 2 + (i & 1);
                    gate_list[e * SEG + p] = sg[i];
                    p++;
                }
            }
        }
    }
}

// ---------------- Kernel C: per-expert gathered GEMM, bf16 MFMA ----------------
// r1 skeleton (verified 99us): BM=128, BN=256, BK=32, LDS ring of 3 slots
// (A[128][32]+B[256][32] = 24KB/slot, 72KB), prefetch depth 2, ONE s_barrier
// per K-tile, counted vmcnt, rotation swizzle slot=(g+(row>>1))&3 with inverse
// rotation pre-applied to the per-lane GLOBAL source address.
// CHANGE vs r1: 8 waves (512 thr), each wave owns 64x64 (acc[4][4] = 64 AGPR,
// ~half the register footprint) -> 2 waves/SIMD co-resident IN ONE BLOCK.
// Intra-block TLP overlaps one wave's ds_read latency/barrier skew with the
// other's MFMA. Per-wave staging = 3 gload_lds per K-tile -> vmcnt(3).

__device__ __forceinline__ void stage_tile(const unsigned short* const* sp,
                                           unsigned short* lbase, int wave, int kt) {
    int ko = kt << 5;   // kt * 32 elements
#pragma unroll
    for (int j = 0; j < 3; ++j) {
        __builtin_amdgcn_global_load_lds(
            (const AS1 void*)(sp[j] + ko),
            (AS3 void*)(lbase + (wave * 3 + j) * 512),
            16, 0, 0);
    }
}

__device__ __forceinline__ void tile_mma(const unsigned short* ba, int aoff, int boff,
                                         f32x4 (&acc)[4][4]) {
    bf16x8 af[4], bf[4];
#pragma unroll
    for (int mi = 0; mi < 4; ++mi) af[mi] = *(const bf16x8*)(ba + aoff + mi * 512);
#pragma unroll
    for (int ni = 0; ni < 4; ++ni) bf[ni] = *(const bf16x8*)(ba + boff + ni * 512);
    __builtin_amdgcn_s_setprio(1);
#pragma unroll
    for (int mi = 0; mi < 4; ++mi)
#pragma unroll
        for (int ni = 0; ni < 4; ++ni)
            acc[mi][ni] = __builtin_amdgcn_mfma_f32_16x16x32_bf16(
                af[mi], bf[ni], acc[mi][ni], 0, 0, 0);
    __builtin_amdgcn_s_setprio(0);
}

template<bool STORE>
__global__ __launch_bounds__(512, 2) void moe_gemm(
    const unsigned short* __restrict__ xb, const unsigned short* __restrict__ web,
    const float* __restrict__ be, const int* __restrict__ cnt,
    const int* __restrict__ tok_list, const float* __restrict__ gate_list,
    unsigned short* __restrict__ Sb, float* __restrict__ outa) {

    extern __shared__ __align__(16) unsigned short lbuf[];  // 3 slots x 12288 el = 72 KB
    __shared__ int   tok_s[128];
    __shared__ float gate_s[128];

    // exact-grid: find (expert, m-tile) from flat blockIdx.y via prefix over cnt
    int id = blockIdx.y, e = 0, c = 0;
    while (e < NEXP) {
        c = cnt[e];
        int mt = (c + 127) >> 7;
        if (id < mt) break;
        id -= mt; e++;
    }
    if (e == NEXP) return;
    int m0 = id << 7;
    int n0 = blockIdx.x << 8;

    int tid = threadIdx.x;
    int w = tid >> 6, lane = tid & 63;
    int wave_m = w >> 2, wave_n = w & 3;   // 2 x 4 wave grid, each owns 64x64

    if (tid < 128) {
        int r = m0 + tid;
        int rc = min(r, c - 1);
        tok_s[tid]  = tok_list[e * SEG + rc];
        gate_s[tid] = (r < c) ? gate_list[e * SEG + rc] : 0.0f;
    }
    __syncthreads();

    // LDS read offsets (elements); rotation slot for 16-aligned rows = (mrow>>1)&3
    int mrow = lane & 15, q = lane >> 4;
    int ksl  = ((q + (mrow >> 1)) & 3) << 3;
    int aoff = (wave_m * 64 + mrow) * 32 + ksl;           // + mi*512
    int boff = 4096 + (wave_n * 64 + mrow) * 32 + ksl;    // + ni*512

    // staging: chunk ch = wave*3+j; ch<8 -> A rows ch*16+sub; ch>=8 -> B rows
    // (ch-8)*16+sub; per-lane source granule pre-rotated (inverse of LDS slot).
    int g0  = ((lane & 3) - ((lane >> 3) & 3)) & 3;
    int sub = lane >> 2;
    const unsigned short* sp[3];
#pragma unroll
    for (int j = 0; j < 3; ++j) {
        int ch = w * 3 + j;
        int arow = min((ch << 4) + sub, 127);
        int brow = ((ch - 8) << 4) + sub;
        const unsigned short* pa = xb + (size_t)(tok_s[arow] >> 1) * DDIM + g0 * 8;
        const unsigned short* pb = web + ((size_t)e << 20) +
                                   (size_t)(n0 + brow) * DDIM + g0 * 8;
        sp[j] = (ch < 8) ? pa : pb;
    }

    f32x4 acc[4][4];
#pragma unroll
    for (int mi = 0; mi < 4; ++mi)
#pragma unroll
        for (int ni = 0; ni < 4; ++ni) acc[mi][ni] = (f32x4){0.f, 0.f, 0.f, 0.f};

    // ---- prologue: stage K-tiles 0,1 (3 loads each per wave; 6 outstanding) ----
    stage_tile(sp, lbuf,         w, 0);
    stage_tile(sp, lbuf + 12288, w, 1);

    // ---- main loop: K-tiles 0..29, stage kt+2, wait vmcnt(3) (tile kt done,
    //      tile kt+1's 3 loads stay in flight across the barrier) ----
    for (int kb = 0; kb < 10; ++kb) {
#pragma unroll
        for (int u = 0; u < 3; ++u) {
            int kt = kb * 3 + u;
            asm volatile("s_waitcnt vmcnt(3)" ::: "memory");
            __builtin_amdgcn_s_barrier();
            asm volatile("" ::: "memory");
            stage_tile(sp, lbuf + ((u + 2) % 3) * 12288, w, kt + 2);
            tile_mma(lbuf + u * 12288, aoff, boff, acc);
        }
    }
    // ---- epilogue tiles 30 (slot 0) and 31 (slot 1) ----
    asm volatile("s_waitcnt vmcnt(3)" ::: "memory");
    __builtin_amdgcn_s_barrier();
    asm volatile("" ::: "memory");
    tile_mma(lbuf, aoff, boff, acc);

    asm volatile("s_waitcnt vmcnt(0)" ::: "memory");
    __builtin_amdgcn_s_barrier();
    asm volatile("" ::: "memory");
    tile_mma(lbuf + 12288, aoff, boff, acc);

    if (STORE) {
        // ---- stage C-tile (gate*(acc+bias), bf16) into LDS, XOR-swizzled ----
        __syncthreads();
#pragma unroll
        for (int ni = 0; ni < 4; ++ni) {
            int col = wave_n * 64 + ni * 16 + mrow;       // tile-local col (0..255)
            float bias = be[e * DDIM + n0 + col];
            int cg = col >> 3, cl = col & 7;
#pragma unroll
            for (int mi = 0; mi < 4; ++mi) {
#pragma unroll
                for (int r = 0; r < 4; ++r) {
                    int row = wave_m * 64 + mi * 16 + q * 4 + r;   // 0..127
                    lbuf[row * 256 + ((cg ^ (row & 7)) << 3) + cl] =
                        f2bf(gate_s[row] * (acc[mi][ni][r] + bias));
                }
            }
        }
        __syncthreads();
        // ---- coalesced 16B stores: 128x32 granules / 512 threads = 8 iters ----
#pragma unroll
        for (int j = 0; j < 8; ++j) {
            int t = j * 512 + tid;
            int row = t >> 5, gc = t & 31;
            u16x8 vv = *(const u16x8*)&lbuf[row * 256 + ((gc ^ (row & 7)) << 3)];
            if (m0 + row < c)
                *(u16x8*)(Sb + (size_t)tok_s[row] * DDIM + n0 + gc * 8) = vv;
        }
    } else {
        __syncthreads();
#pragma unroll
        for (int ni = 0; ni < 4; ++ni) {
            int col = n0 + wave_n * 64 + ni * 16 + mrow;
            float bias = be[e * DDIM + col];
#pragma unroll
            for (int mi = 0; mi < 4; ++mi) {
#pragma unroll
                for (int r = 0; r < 4; ++r) {
                    int rl = wave_m * 64 + mi * 16 + q * 4 + r;
                    if (m0 + rl < c)
                        atomicAdd(outa + (size_t)(tok_s[rl] >> 1) * DDIM + col,
                                  gate_s[rl] * (acc[mi][ni][r] + bias));
                }
            }
        }
    }
}

// ---------------- Kernel D: combine the two slot rows per token ----------------
__global__ void combine(const unsigned short* __restrict__ S, float* __restrict__ out) {
    size_t i = (size_t)blockIdx.x * 256 + threadIdx.x;
    size_t t = i >> 7;
    size_t g = i & 127;
    const u16x8* r0 = (const u16x8*)(S + t * 2 * DDIM) + g;
    const u16x8* r1 = (const u16x8*)(S + (t * 2 + 1) * DDIM) + g;
    u16x8 a = *r0;
    u16x8 b = *r1;
    f32x4 o0, o1;
#pragma unroll
    for (int k = 0; k < 4; k++) o0[k] = bf2f(a[k]) + bf2f(b[k]);
#pragma unroll
    for (int k = 0; k < 4; k++) o1[k] = bf2f(a[4 + k]) + bf2f(b[4 + k]);
    f32x4* op = (f32x4*)(out + t * DDIM + g * 8);
    __builtin_nontemporal_store(o0, op);
    __builtin_nontemporal_store(o1, op + 1);
}

extern "C" void kernel_launch(void* const* d_in, const int* in_sizes, int n_in,
                              void* d_out, int out_size, void* d_ws, size_t ws_size,
                              hipStream_t stream) {
    const float* x  = (const float*)d_in[0];
    const float* Wg = (const float*)d_in[1];
    const float* bg = (const float*)d_in[2];
    const float* We = (const float*)d_in[3];
    const float* be = (const float*)d_in[4];
    float* out = (float*)d_out;

    char* ws = (char*)d_ws;
    unsigned short* xb  = (unsigned short*)ws;                          // 32 MB
    unsigned short* web = (unsigned short*)(ws + 33554432);             // 16 MB
    int*   tok_list  = (int*)(ws + 33554432 + 16777216);                // 512 KB
    float* gate_list = (float*)(ws + 33554432 + 16777216 + 524288);     // 512 KB
    int*   cnt       = (int*)(ws + 33554432 + 16777216 + 1048576);      // 32 B
    unsigned short* S = (unsigned short*)(ws + 52428800);               // 67.1 MB

    const size_t NEED = 52428800ull + (size_t)32768 * DDIM * 2;         // ~119.5 MB

    // one-time opt-in for 72KB dynamic LDS
    static bool attr_done = false;
    if (!attr_done) {
        hipFuncSetAttribute(reinterpret_cast<const void*>(moe_gemm<true>),
                            hipFuncAttributeMaxDynamicSharedMemorySize, 73728);
        hipFuncSetAttribute(reinterpret_cast<const void*>(moe_gemm<false>),
                            hipFuncAttributeMaxDynamicSharedMemorySize, 73728);
        attr_done = true;
    }

    hipMemsetAsync(cnt, 0, NEXP * sizeof(int), stream);

    // 512 gating blocks + 2048 convert blocks in one dispatch
    prep<<<2560, 512, 0, stream>>>(x, Wg, bg, We, xb, web, cnt, tok_list, gate_list);

    if (ws_size >= NEED) {
        // grid.y = 264: max total m-tiles = 32768/128 + 8 ceil-partials; x = 4 n-tiles
        moe_gemm<true><<<dim3(4, 264), 512, 73728, stream>>>(
            xb, web, be, cnt, tok_list, gate_list, S, nullptr);
        combine<<<8192, 256, 0, stream>>>(S, out);
    } else {
        hipMemsetAsync(d_out, 0, (size_t)out_size * sizeof(float), stream);
        moe_gemm<false><<<dim3(4, 264), 512, 73728, stream>>>(
            xb, web, be, cnt, tok_list, gate_list, nullptr, out);
    }
}